// Round 9
// baseline (299.712 us; speedup 1.0000x reference)
//
#include <hip/hip_runtime.h>
#include <hip/hip_bf16.h>
#include <stdint.h>

#define B_   2
#define N_   2048
#define H_   16
#define DQK_ 128
#define DV_  128
#define E_   2048
#define CH_  64
#define NC_  32
#define M_   (B_*N_)   // 4096
#define QKVG_LD 8192
#define ROT_C 0.21091607f            // log2(10000)/63
#define KS_   0.08838834764831843f   // 1/sqrt(128)

using bf16x8 = __attribute__((ext_vector_type(8))) __bf16;
using f32x4  = __attribute__((ext_vector_type(4))) float;
typedef __hip_bfloat16 bf16_t;

__device__ __forceinline__ void gload_lds16(const void* g, void* l) {
  __builtin_amdgcn_global_load_lds(
      (const __attribute__((address_space(1))) void*)(uintptr_t)g,
      (__attribute__((address_space(3))) void*)(uint32_t)(uintptr_t)l,
      16, 0, 0);
}

__device__ __forceinline__ float head_log2g(int h) {
  return (float)(log2(1.0 - exp2((double)(-5 - h))));
}

__device__ __forceinline__ float bfu2f(unsigned short u) {
  unsigned int t = (unsigned int)u << 16; float f;
  __builtin_memcpy(&f, &t, 4); return f;
}
__device__ __forceinline__ unsigned short f2bfu(float f) {
  bf16_t b = __float2bfloat16(f);
  unsigned short u; __builtin_memcpy(&u, &b, 2); return u;
}

// ------- fused f32->bf16 converts + bias concat + rotary trig table --------
__global__ __launch_bounds__(256)
void cvt_all_kernel(const float* __restrict__ x,
                    const float* __restrict__ Wq, const float* __restrict__ Wk,
                    const float* __restrict__ Wv, const float* __restrict__ Wg,
                    const float* __restrict__ Wo,
                    const float* __restrict__ bq, const float* __restrict__ bk,
                    const float* __restrict__ bv, const float* __restrict__ bg,
                    const int* __restrict__ startp,
                    bf16_t* __restrict__ xb, bf16_t* __restrict__ wcat,
                    bf16_t* __restrict__ wob, float* __restrict__ bcat,
                    float2* __restrict__ trig) {
  const int NX = 2097152, NW = 1048576;
  int g = blockIdx.x * 256 + threadIdx.x;
  const float* s; bf16_t* d; int si, di;
  if (g < NX) { s = x; si = g; d = xb; di = g; }
  else if (g < NX + 4*NW) {
    int t = g - NX; int r = t / NW; si = t - r*NW;
    s = (r==0) ? Wq : (r==1) ? Wk : (r==2) ? Wv : Wg; d = wcat; di = t;
  } else if (g < NX + 5*NW) {
    si = g - NX - 4*NW; s = Wo; d = wob; di = si;
  } else if (g < NX + 5*NW + 2048) {
    int j = g - (NX + 5*NW);                 // 0..2047
    int which = j >> 9, i = j & 511;
    const float* bs = (which==0) ? bq : (which==1) ? bk : (which==2) ? bv : bg;
    ((float4*)bcat)[which*512 + i] = ((const float4*)bs)[i];
    return;
  } else {
    int g2 = g - (NX + 5*NW + 2048);         // 0..131071
    if (g2 < 131072) {
      int n = g2 >> 6, j = g2 & 63;
      float ang = (float)(startp[0] + n) * exp2f(-ROT_C * (float)j);
      float sn, cn; sincosf(ang, &sn, &cn);
      trig[g2] = make_float2(cn, sn);
    }
    return;
  }
  float4 v = ((const float4*)s)[si];
  ushort4 p;
  p.x = f2bfu(v.x); p.y = f2bfu(v.y); p.z = f2bfu(v.z); p.w = f2bfu(v.w);
  ((ushort4*)d)[di] = p;
}

// ============ 256xBN 8-phase GEMM: C = A[M,K] @ Bw[N,K]^T + bias ============
// BN = 64*NSUB. 8 waves (2M x 4N), BK=64, double-buffered LDS, single barrier
// per phase. r9: B-prefetch spread across p2/p3 -> even 4/4/6/6 ds_read/phase.
// Waits: vmcnt(4)@p1 [R2: next-tile B drained for all waves before p2 bnx
// reads, via p1-end barrier], vmcnt(4|2)@p3 [R1: next-tile A drained before
// next p0], vmcnt(0) at kt==NKT-2. WAR on staged regions ordered by barriers.
template<bool OUT_BF16, int NSUB>
__global__ __launch_bounds__(512, 2)
void gemm8_kernel(const bf16_t* __restrict__ A, const bf16_t* __restrict__ Bw,
                  const float* __restrict__ bias, void* __restrict__ Cout,
                  int K, int ldc, int tilesM) {
  extern __shared__ char smem[];
  const int nwg = gridDim.x;
  const int bid = blockIdx.x;
  const int cpx = nwg >> 3;                      // nwg % 8 == 0 guaranteed
  const int swz = (bid & 7) * cpx + (bid >> 3);  // XCD-bijective
  const int tm = swz % tilesM, tn = swz / tilesM;
  const int rowT0 = tm * 256, colT0 = tn * (64 * NSUB);
  const int tid = threadIdx.x, wave = tid >> 6, lane = tid & 63;
  const int wr = wave >> 2, wc = wave & 3;
  const int l16 = lane & 15, lhi = lane >> 4;
  const int NKT = K >> 6;

  const int sw = ((tid & 7) * 16) ^ (((tid >> 3) & 7) << 4);
  const size_t aOff = (size_t)(rowT0 + (tid >> 3)) * K + (sw >> 1);
  const size_t bOff = (size_t)(colT0 + (tid >> 3)) * K + (sw >> 1);
  const uint32_t wl = wave * 1024;

  auto stage = [&](int h) {
    const int ktp = h >> 2, r = h & 3, buf = ktp & 1;
    const int k0 = ktp << 6;
    if (r < 2) {                               // B half r
      const uint32_t base = 65536u + buf * (8192u*NSUB) + r * (4096u*NSUB) + wl;
#pragma unroll
      for (int L = 0; L < NSUB/2; L++)
        gload_lds16(Bw + bOff + (size_t)(r * (NSUB*32) + L * 64) * K + k0,
                    smem + base + L * 8192);
    } else {                                   // A half r-2
      const int half = r - 2;
      const uint32_t base = buf * 32768u + half * 16384u + wl;
#pragma unroll
      for (int L = 0; L < 2; L++)
        gload_lds16(A + aOff + (size_t)(half * 128 + L * 64) * K + k0,
                    smem + base + L * 8192);
    }
  };

  for (int h = 0; h < 6; h++) stage(h);
  if constexpr (NSUB == 4) asm volatile("s_waitcnt vmcnt(4)" ::: "memory");
  else                     asm volatile("s_waitcnt vmcnt(2)" ::: "memory");
  __builtin_amdgcn_s_barrier();
  asm volatile("" ::: "memory");
  __builtin_amdgcn_sched_barrier(0);

  f32x4 acc[8][NSUB] = {};
  bf16x8 bfr[NSUB][2], bnx[NSUB][2];

  // initial next-B = kt0's B (buf0); prologue vmcnt drained halves 0..3
#pragma unroll
  for (int n = 0; n < NSUB; n++) {
    const int r = wc * (16*NSUB) + n * 16 + l16;
#pragma unroll
    for (int ks = 0; ks < 2; ks++) {
      const int cb = ks * 64 + lhi * 16;
      bnx[n][ks] = *(const bf16x8*)(smem + 65536u + r * 128 + (cb ^ ((r & 7) << 4)));
    }
  }

  for (int kt = 0; kt < NKT; kt++) {
    const int cur = kt & 1;
    const uint32_t aB = cur * 32768u;
    const uint32_t bN = 65536u + ((kt + 1) & 1) * (8192u*NSUB);
#pragma unroll
    for (int p = 0; p < 4; p++) {
      if (p == 0) {
#pragma unroll
        for (int n = 0; n < NSUB; n++)
#pragma unroll
          for (int ks = 0; ks < 2; ks++) bfr[n][ks] = bnx[n][ks];
      }
      // next-tile B prefetch, spread: p2 -> n 0..NSUB/2, p3 -> rest.
      // Safe: p1's vmcnt(4)+barrier guarantees next B0/B1 landed (all waves).
      if (kt + 1 < NKT && (p == 2 || p == 3)) {
        const int nlo = (p == 2) ? 0 : NSUB/2;
        const int nhi = (p == 2) ? NSUB/2 : NSUB;
        for (int n = nlo; n < nhi; n++) {
          const int r = wc * (16*NSUB) + n * 16 + l16;
#pragma unroll
          for (int ks = 0; ks < 2; ks++) {
            const int cb = ks * 64 + lhi * 16;
            bnx[n][ks] = *(const bf16x8*)(smem + bN + r * 128 + (cb ^ ((r & 7) << 4)));
          }
        }
      }
      bf16x8 afr[2][2];
#pragma unroll
      for (int mm = 0; mm < 2; mm++) {
        const int r = wr * 128 + p * 32 + mm * 16 + l16;
#pragma unroll
        for (int ks = 0; ks < 2; ks++) {
          const int cb = ks * 64 + lhi * 16;
          afr[mm][ks] = *(const bf16x8*)(smem + aB + r * 128 + (cb ^ ((r & 7) << 4)));
        }
      }
      const int h = 4 * kt + p + 6;
      if (h < 4 * NKT) stage(h);
      __builtin_amdgcn_sched_barrier(0);       // loads+stage issued before MFMA
      __builtin_amdgcn_s_setprio(1);
#pragma unroll
      for (int mm = 0; mm < 2; mm++)
#pragma unroll
        for (int n = 0; n < NSUB; n++)
#pragma unroll
          for (int ks = 0; ks < 2; ks++)
            acc[2 * p + mm][n] = __builtin_amdgcn_mfma_f32_16x16x32_bf16(
                afr[mm][ks], bfr[n][ks], acc[2 * p + mm][n], 0, 0, 0);
      __builtin_amdgcn_s_setprio(0);
      if (p == 1) {
        asm volatile("s_waitcnt vmcnt(4)" ::: "memory");   // R2 (both NSUB)
      }
      if (p == 3) {
        if (kt < NKT - 2) {
          if constexpr (NSUB == 4) asm volatile("s_waitcnt vmcnt(4)" ::: "memory");
          else                     asm volatile("s_waitcnt vmcnt(2)" ::: "memory");
        } else if (kt == NKT - 2) {
          asm volatile("s_waitcnt vmcnt(0)" ::: "memory");
        }
      }
      __builtin_amdgcn_s_barrier();            // single per-phase rendezvous
      asm volatile("" ::: "memory");
      __builtin_amdgcn_sched_barrier(0);
    }
  }

#pragma unroll
  for (int m = 0; m < 8; m++) {
    const int rbase = rowT0 + wr * 128 + m * 16 + lhi * 4;
#pragma unroll
    for (int n = 0; n < NSUB; n++) {
      const int col = colT0 + wc * (16*NSUB) + n * 16 + l16;
      const float bv = bias[col];
#pragma unroll
      for (int j = 0; j < 4; j++) {
        float v = acc[m][n][j] + bv;
        if (OUT_BF16) ((bf16_t*)Cout)[(size_t)(rbase + j) * ldc + col] = __float2bfloat16(v);
        else          ((float*)Cout)[(size_t)(rbase + j) * ldc + col] = v;
      }
    }
  }
}

// ------- per-chunk KV^T = V^T . K'  (rotary-on-k via trig table) ------------
__global__ __launch_bounds__(256)
void chunk_kvt_kernel(const bf16_t* __restrict__ kb, const bf16_t* __restrict__ vb,
                      const float2* __restrict__ trig, bf16_t* __restrict__ kvt) {
  __shared__ alignas(16) char lds[32768];
  char* vts = lds;
  char* kts = lds + 16384;

  const int tid = threadIdx.x, wave = tid >> 6, lane = tid & 63;
  const int l16 = lane & 15, lhi = lane >> 4;
  const int blk = blockIdx.x;              // bh*NC + ch
  const int bh = blk >> 5, ch = blk & 31;
  const int h = bh & (H_ - 1);
  const float log2g = head_log2g(h);
  const int n0 = ch * 64;

  const size_t bhbase = (size_t)(bh >> 4) * N_ * QKVG_LD + (size_t)h * 128;

#pragma unroll
  for (int it = 0; it < 4; it++) {
    int j = it*16 + (tid >> 4);
    int e0 = (tid & 15) * 8;
    bf16x8 vv = *(const bf16x8*)(vb + bhbase + (size_t)(n0 + j)*QKVG_LD + e0);
    bf16x8 kk = *(const bf16x8*)(kb + bhbase + (size_t)(n0 + j)*QKVG_LD + e0);
    const float2* tr = trig + (size_t)(n0 + j)*64 + (tid & 15)*4;
    float kvd = exp2f((float)(63 - j) * log2g) * KS_;
    float kr[8];
#pragma unroll
    for (int p = 0; p < 4; p++) {
      float2 cs = tr[p];
      float a = (float)kk[2*p], b2 = (float)kk[2*p+1];
      kr[2*p]   = (a*cs.x - b2*cs.y);
      kr[2*p+1] = (b2*cs.x + a*cs.y);
    }
#pragma unroll
    for (int m = 0; m < 8; m++) {
      int e = e0 + m;
      *(__bf16*)(vts + e*128 + ((j*2) ^ ((e&7)<<4))) = vv[m];
      *(__bf16*)(kts + e*128 + ((j*2) ^ ((e&7)<<4))) = (__bf16)(kr[m] * kvd);
    }
  }
  __syncthreads();

  f32x4 acc[2][8] = {};
#pragma unroll
  for (int kk2 = 0; kk2 < 2; kk2++) {
#pragma unroll
    for (int et = 0; et < 2; et++) {
      int e = (2*wave + et)*16 + l16;
      bf16x8 vf = *(const bf16x8*)(vts + e*128 + (((kk2*32 + lhi*8)*2) ^ ((e&7)<<4)));
#pragma unroll
      for (int dt = 0; dt < 8; dt++) {
        int d = dt*16 + l16;
        bf16x8 kf = *(const bf16x8*)(kts + d*128 + (((kk2*32 + lhi*8)*2) ^ ((d&7)<<4)));
        acc[et][dt] = __builtin_amdgcn_mfma_f32_16x16x32_bf16(vf, kf, acc[et][dt], 0, 0, 0);
      }
    }
  }

  const size_t obase = (size_t)blk * 16384;
#pragma unroll
  for (int et = 0; et < 2; et++)
#pragma unroll
    for (int dt = 0; dt < 8; dt++)
#pragma unroll
      for (int j = 0; j < 4; j++) {
        int e = (2*wave + et)*16 + lhi*4 + j;
        int d = dt*16 + l16;
        kvt[obase + e*128 + d] = __float2bfloat16(acc[et][dt][j]);
      }
}

// ---------------- state scan over chunks (2 elems/thread) ------------------
__global__ __launch_bounds__(256)
void state_scan_kernel(const bf16_t* __restrict__ kvt, const float* __restrict__ prev,
                       bf16_t* __restrict__ sbft, float* __restrict__ out_state) {
  int t = blockIdx.x * 256 + threadIdx.x;     // over B*H*8192
  int bh = t >> 13;
  int ed = (t & 8191) * 2;
  int e = ed >> 7, d = ed & 127;              // d even, d+1 same e
  int h = bh & (H_ - 1);
  const float cdecay = exp2f(64.0f * head_log2g(h));

  float S0 = prev[(size_t)bh*16384 + (size_t)d*128 + e];
  float S1 = prev[(size_t)bh*16384 + (size_t)(d+1)*128 + e];
  size_t boff = ((size_t)bh * (NC_*16384) + ed) >> 1;     // uint index
  const unsigned int* kv2 = (const unsigned int*)kvt;
  unsigned int* sb2 = (unsigned int*)sbft;
  for (int ch = 0; ch < NC_; ch++) {
    sb2[boff] = (unsigned int)f2bfu(S0) | ((unsigned int)f2bfu(S1) << 16);
    unsigned int kv = kv2[boff];
    S0 = S0 * cdecay + bfu2f((unsigned short)(kv & 0xffff));
    S1 = S1 * cdecay + bfu2f((unsigned short)(kv >> 16));
    boff += 8192;
  }
  out_state[(size_t)bh*16384 + (size_t)d*128 + e]     = S0;
  out_state[(size_t)bh*16384 + (size_t)(d+1)*128 + e] = S1;
}

// --- per-chunk output + fused GroupNorm*SiLU(gate), rotary via trig table ---
__global__ __launch_bounds__(256)
void chunk_out_kernel(const bf16_t* __restrict__ qb, const bf16_t* __restrict__ kb,
                      const bf16_t* __restrict__ vb, const bf16_t* __restrict__ gb,
                      const bf16_t* __restrict__ sbft, const float2* __restrict__ trig,
                      bf16_t* __restrict__ gated) {
  __shared__ alignas(16) char lds[32768];
  char* vts = lds;                 // V^T 16KB   (phase 1)
  char* ats = lds + 16384;         // att 8KB    (phase 1)
  float* o_lds = (float*)lds;      // 64x128 f32 (phase 2, after barrier)

  const int tid = threadIdx.x, wave = tid >> 6, lane = tid & 63;
  const int l16 = lane & 15, lhi = lane >> 4;
  const int blk = blockIdx.x;              // bh*NC + ch
  const int bh = blk >> 5, ch = blk & 31;
  const int h = bh & (H_ - 1);
  const int b = bh >> 4;
  const float log2g = head_log2g(h);
  const int n0 = ch * 64;

  const size_t bhbase = (size_t)b * N_ * QKVG_LD + (size_t)h * 128;
  const bf16_t* Srow = sbft + (size_t)blk * 16384;   // [e][d]

#pragma unroll
  for (int it = 0; it < 4; it++) {
    int j = it*16 + (tid >> 4);
    int e0 = (tid & 15) * 8;
    bf16x8 vv = *(const bf16x8*)(vb + bhbase + (size_t)(n0 + j)*QKVG_LD + e0);
#pragma unroll
    for (int m = 0; m < 8; m++) {
      int e = e0 + m;
      *(__bf16*)(vts + e*128 + ((j*2) ^ ((e&7)<<4))) = vv[m];
    }
  }

  // q fragments with rotary (row = n0 + wave*16 + l16)
  const float2* trq = trig + (size_t)(n0 + wave*16 + l16)*64;
  bf16x8 qf[4];
#pragma unroll
  for (int dk = 0; dk < 4; dk++) {
    bf16x8 qv = *(const bf16x8*)(qb + bhbase + (size_t)(n0 + wave*16 + l16)*QKVG_LD + dk*32 + lhi*8);
#pragma unroll
    for (int p = 0; p < 4; p++) {
      float2 cs = trq[dk*16 + lhi*4 + p];
      float a = (float)qv[2*p], b2 = (float)qv[2*p+1];
      qf[dk][2*p]   = (__bf16)(a*cs.x - b2*cs.y);
      qf[dk][2*p+1] = (__bf16)(b2*cs.x + a*cs.y);
    }
  }

  // att = (q k^T) * Dmat, rotary+KS on k fragments
  f32x4 aacc[4] = {};
#pragma unroll
  for (int jt = 0; jt < 4; jt++) {
    const float2* trk = trig + (size_t)(n0 + jt*16 + l16)*64;
#pragma unroll
    for (int dk = 0; dk < 4; dk++) {
      bf16x8 kv = *(const bf16x8*)(kb + bhbase + (size_t)(n0 + jt*16 + l16)*QKVG_LD + dk*32 + lhi*8);
      bf16x8 kf;
#pragma unroll
      for (int p = 0; p < 4; p++) {
        float2 cs = trk[dk*16 + lhi*4 + p];
        float a = (float)kv[2*p], b2 = (float)kv[2*p+1];
        kf[2*p]   = (__bf16)((a*cs.x - b2*cs.y) * KS_);
        kf[2*p+1] = (__bf16)((b2*cs.x + a*cs.y) * KS_);
      }
      aacc[jt] = __builtin_amdgcn_mfma_f32_16x16x32_bf16(qf[dk], kf, aacc[jt], 0, 0, 0);
    }
  }
#pragma unroll
  for (int jt = 0; jt < 4; jt++)
#pragma unroll
    for (int j = 0; j < 4; j++) {
      int i = wave*16 + lhi*4 + j;
      int jc = jt*16 + l16;
      aacc[jt][j] *= (i >= jc) ? exp2f((float)(i - jc) * log2g) : 0.0f;
    }

#pragma unroll
  for (int jt = 0; jt < 4; jt++)
#pragma unroll
    for (int j = 0; j < 4; j++) {
      int i = wave*16 + lhi*4 + j;
      int jc = jt*16 + l16;
      *(__bf16*)(ats + i*128 + ((jc*2) ^ ((i&7)<<4))) = (__bf16)aacc[jt][j];
    }
  __syncthreads();

  f32x4 oacc[8] = {};
#pragma unroll
  for (int et = 0; et < 8; et++) {
#pragma unroll
    for (int dk = 0; dk < 4; dk++) {
      int e = et*16 + l16;
      bf16x8 sf = *(const bf16x8*)(Srow + e*128 + dk*32 + lhi*8);
      oacc[et] = __builtin_amdgcn_mfma_f32_16x16x32_bf16(qf[dk], sf, oacc[et], 0, 0, 0);
    }
  }
#pragma unroll
  for (int j = 0; j < 4; j++) {
    int i = wave*16 + lhi*4 + j;
    float f = exp2f((float)(i + 1) * log2g);
#pragma unroll
    for (int et = 0; et < 8; et++) oacc[et][j] *= f;
  }

#pragma unroll
  for (int kk2 = 0; kk2 < 2; kk2++) {
    int i = wave*16 + l16;
    bf16x8 af = *(const bf16x8*)(ats + i*128 + (((kk2*32 + lhi*8)*2) ^ ((i&7)<<4)));
#pragma unroll
    for (int et = 0; et < 8; et++) {
      int e = et*16 + l16;
      bf16x8 vf = *(const bf16x8*)(vts + e*128 + (((kk2*32 + lhi*8)*2) ^ ((e&7)<<4)));
      oacc[et] = __builtin_amdgcn_mfma_f32_16x16x32_bf16(af, vf, oacc[et], 0, 0, 0);
    }
  }

  __syncthreads();
#pragma unroll
  for (int et = 0; et < 8; et++)
#pragma unroll
    for (int j = 0; j < 4; j++) {
      int i = wave*16 + lhi*4 + j;
      o_lds[i*128 + et*16 + l16] = oacc[et][j];
    }
  __syncthreads();

  for (int rr = 0; rr < 16; rr++) {
    int r = wave*16 + rr;
    float2 xv = *(const float2*)&o_lds[r*128 + lane*2];
    float s = xv.x + xv.y, ss = xv.x*xv.x + xv.y*xv.y;
#pragma unroll
    for (int off = 1; off < 64; off <<= 1) {
      s  += __shfl_xor(s, off);
      ss += __shfl_xor(ss, off);
    }
    float mu  = s * (1.0f/128.0f);
    float inv = rsqrtf(ss * (1.0f/128.0f) - mu*mu + 1e-6f);
    size_t grow = (size_t)b * N_ + (n0 + r);
    unsigned int gg = *(const unsigned int*)(gb + grow*QKVG_LD + h*128 + lane*2);
    float g0 = bfu2f((unsigned short)(gg & 0xffff));
    float g1 = bfu2f((unsigned short)(gg >> 16));
    float r0 = (xv.x - mu) * inv * (g0 / (1.0f + expf(-g0)));
    float r1 = (xv.y - mu) * inv * (g1 / (1.0f + expf(-g1)));
    ushort2 o2; o2.x = f2bfu(r0); o2.y = f2bfu(r1);
    *(ushort2*)(gated + grow*2048 + h*128 + lane*2) = o2;
  }
}

// ---------------- launch ----------------
extern "C" void kernel_launch(void* const* d_in, const int* in_sizes, int n_in,
                              void* d_out, int out_size, void* d_ws, size_t ws_size,
                              hipStream_t stream) {
  const float* x    = (const float*)d_in[0];
  const float* prev = (const float*)d_in[1];
  const float* Wq = (const float*)d_in[2];  const float* bq = (const float*)d_in[3];
  const float* Wk = (const float*)d_in[4];  const float* bk = (const float*)d_in[5];
  const float* Wv = (const float*)d_in[6];  const float* bv = (const float*)d_in[7];
  const float* Wg = (const float*)d_in[8];  const float* bg = (const float*)d_in[9];
  const float* Wo = (const float*)d_in[10]; const float* bo = (const float*)d_in[11];
  const int* startp = (const int*)d_in[12];

  float* out = (float*)d_out;                               // B*N*E
  float* out_state = out + (size_t)B_*N_*E_;                // B*H*DQK*DV
  float2* trig = (float2*)out;   // 1MB at d_out head; dead until final GEMM

  char* w = (char*)d_ws;
  const size_t XN = (size_t)B_*N_*E_;       // 8388608
  const size_t WN = (size_t)E_*E_;          // 4194304
  bf16_t* xb   = (bf16_t*)w;             w += XN*2;                  // 16MB (reused as gated)
  bf16_t* qkvg = (bf16_t*)w;             w += (size_t)M_*QKVG_LD*2;  // 64MB
  bf16_t* wob  = (bf16_t*)w;             w += WN*2;                  // 8MB
  char*   wcat_region = w;               w += 4*WN*2;                // 32MB
  bf16_t* wcat = (bf16_t*)wcat_region;
  bf16_t* sbft = (bf16_t*)w;             w += (size_t)B_*H_*NC_*16384*2; // 32MB
  bf16_t* kvt   = (bf16_t*)wcat_region;  // alias (wcat dead after QKVG GEMM)
  float*  bcat  = (float*)sbft;   // 32KB at sbft head; consumed before state_scan

  hipFuncSetAttribute(reinterpret_cast<const void*>(gemm8_kernel<true,4>),
                      hipFuncAttributeMaxDynamicSharedMemorySize, 131072);
  hipFuncSetAttribute(reinterpret_cast<const void*>(gemm8_kernel<false,2>),
                      hipFuncAttributeMaxDynamicSharedMemorySize, 98304);

  cvt_all_kernel<<<29192, 256, 0, stream>>>(x, Wq, Wk, Wv, Wg, Wo, bq, bk, bv, bg,
                                            startp, xb, wcat, wob, bcat, trig);

  // fused QKVG projection: [4096,2048] @ [8192,2048]^T -> [4096,8192]
  gemm8_kernel<true,4><<<512, 512, 131072, stream>>>(xb, wcat, bcat, (void*)qkvg,
                                                     E_, QKVG_LD, 16 /*tilesM*/);

  chunk_kvt_kernel<<<B_*H_*NC_, 256, 0, stream>>>(qkvg + 2048, qkvg + 4096,
                                                  trig, kvt);
  state_scan_kernel<<<1024, 256, 0, stream>>>(kvt, prev, sbft, out_state);
  chunk_out_kernel<<<B_*H_*NC_, 256, 0, stream>>>(qkvg, qkvg + 2048, qkvg + 4096,
                                                  qkvg + 6144, sbft, trig,
                                                  xb /*gated*/);

  // output projection: [4096,2048] @ [2048,2048]^T -> [4096,2048] f32
  gemm8_kernel<false,2><<<256, 512, 98304, stream>>>(xb, wob, bo, (void*)out,
                                                     E_, E_, 16 /*tilesM*/);
}

// Round 10
// 279.538 us; speedup vs baseline: 1.0722x; 1.0722x over previous
//
#include <hip/hip_runtime.h>
#include <hip/hip_bf16.h>
#include <stdint.h>

#define B_   2
#define N_   2048
#define H_   16
#define DQK_ 128
#define DV_  128
#define E_   2048
#define CH_  64
#define NC_  32
#define M_   (B_*N_)   // 4096
#define QKVG_LD 8192
#define ROT_C 0.21091607f            // log2(10000)/63
#define KS_   0.08838834764831843f   // 1/sqrt(128)

using bf16x8 = __attribute__((ext_vector_type(8))) __bf16;
using f32x4  = __attribute__((ext_vector_type(4))) float;
typedef __hip_bfloat16 bf16_t;

__device__ __forceinline__ void gload_lds16(const void* g, void* l) {
  __builtin_amdgcn_global_load_lds(
      (const __attribute__((address_space(1))) void*)(uintptr_t)g,
      (__attribute__((address_space(3))) void*)(uint32_t)(uintptr_t)l,
      16, 0, 0);
}

__device__ __forceinline__ float head_log2g(int h) {
  return (float)(log2(1.0 - exp2((double)(-5 - h))));
}

__device__ __forceinline__ float bfu2f(unsigned short u) {
  unsigned int t = (unsigned int)u << 16; float f;
  __builtin_memcpy(&f, &t, 4); return f;
}
__device__ __forceinline__ unsigned short f2bfu(float f) {
  bf16_t b = __float2bfloat16(f);
  unsigned short u; __builtin_memcpy(&u, &b, 2); return u;
}

// ------- fused f32->bf16 converts + bias concat + rotary trig table --------
__global__ __launch_bounds__(256)
void cvt_all_kernel(const float* __restrict__ x,
                    const float* __restrict__ Wq, const float* __restrict__ Wk,
                    const float* __restrict__ Wv, const float* __restrict__ Wg,
                    const float* __restrict__ Wo,
                    const float* __restrict__ bq, const float* __restrict__ bk,
                    const float* __restrict__ bv, const float* __restrict__ bg,
                    const int* __restrict__ startp,
                    bf16_t* __restrict__ xb, bf16_t* __restrict__ wcat,
                    bf16_t* __restrict__ wob, float* __restrict__ bcat,
                    float2* __restrict__ trig) {
  const int NX = 2097152, NW = 1048576;
  int g = blockIdx.x * 256 + threadIdx.x;
  const float* s; bf16_t* d; int si, di;
  if (g < NX) { s = x; si = g; d = xb; di = g; }
  else if (g < NX + 4*NW) {
    int t = g - NX; int r = t / NW; si = t - r*NW;
    s = (r==0) ? Wq : (r==1) ? Wk : (r==2) ? Wv : Wg; d = wcat; di = t;
  } else if (g < NX + 5*NW) {
    si = g - NX - 4*NW; s = Wo; d = wob; di = si;
  } else if (g < NX + 5*NW + 2048) {
    int j = g - (NX + 5*NW);                 // 0..2047
    int which = j >> 9, i = j & 511;
    const float* bs = (which==0) ? bq : (which==1) ? bk : (which==2) ? bv : bg;
    ((float4*)bcat)[which*512 + i] = ((const float4*)bs)[i];
    return;
  } else {
    int g2 = g - (NX + 5*NW + 2048);         // 0..131071
    if (g2 < 131072) {
      int n = g2 >> 6, j = g2 & 63;
      float ang = (float)(startp[0] + n) * exp2f(-ROT_C * (float)j);
      float sn, cn; sincosf(ang, &sn, &cn);
      trig[g2] = make_float2(cn, sn);
    }
    return;
  }
  float4 v = ((const float4*)s)[si];
  ushort4 p;
  p.x = f2bfu(v.x); p.y = f2bfu(v.y); p.z = f2bfu(v.z); p.w = f2bfu(v.w);
  ((ushort4*)d)[di] = p;
}

// ============ 256xBN 8-phase GEMM (r8 configuration — local optimum) ========
// BN = 64*NSUB. 8 waves (2M x 4N), BK=64, double-buffered LDS, single barrier
// per phase, bnx[2] prefetch at p3, vmcnt(6|5)@p2 / vmcnt(4|2)@p3.
template<bool OUT_BF16, int NSUB>
__global__ __launch_bounds__(512, 2)
void gemm8_kernel(const bf16_t* __restrict__ A, const bf16_t* __restrict__ Bw,
                  const float* __restrict__ bias, void* __restrict__ Cout,
                  int K, int ldc, int tilesM) {
  extern __shared__ char smem[];
  const int nwg = gridDim.x;
  const int bid = blockIdx.x;
  const int cpx = nwg >> 3;                      // nwg % 8 == 0 guaranteed
  const int swz = (bid & 7) * cpx + (bid >> 3);  // XCD-bijective
  const int tm = swz % tilesM, tn = swz / tilesM;
  const int rowT0 = tm * 256, colT0 = tn * (64 * NSUB);
  const int tid = threadIdx.x, wave = tid >> 6, lane = tid & 63;
  const int wr = wave >> 2, wc = wave & 3;
  const int l16 = lane & 15, lhi = lane >> 4;
  const int NKT = K >> 6;

  const int sw = ((tid & 7) * 16) ^ (((tid >> 3) & 7) << 4);
  const size_t aOff = (size_t)(rowT0 + (tid >> 3)) * K + (sw >> 1);
  const size_t bOff = (size_t)(colT0 + (tid >> 3)) * K + (sw >> 1);
  const uint32_t wl = wave * 1024;

  auto stage = [&](int h) {
    const int ktp = h >> 2, r = h & 3, buf = ktp & 1;
    const int k0 = ktp << 6;
    if (r < 2) {                               // B half r
      const uint32_t base = 65536u + buf * (8192u*NSUB) + r * (4096u*NSUB) + wl;
#pragma unroll
      for (int L = 0; L < NSUB/2; L++)
        gload_lds16(Bw + bOff + (size_t)(r * (NSUB*32) + L * 64) * K + k0,
                    smem + base + L * 8192);
    } else {                                   // A half r-2
      const int half = r - 2;
      const uint32_t base = buf * 32768u + half * 16384u + wl;
#pragma unroll
      for (int L = 0; L < 2; L++)
        gload_lds16(A + aOff + (size_t)(half * 128 + L * 64) * K + k0,
                    smem + base + L * 8192);
    }
  };

  for (int h = 0; h < 6; h++) stage(h);
  if constexpr (NSUB == 4) asm volatile("s_waitcnt vmcnt(4)" ::: "memory");
  else                     asm volatile("s_waitcnt vmcnt(2)" ::: "memory");
  __builtin_amdgcn_s_barrier();
  asm volatile("" ::: "memory");
  __builtin_amdgcn_sched_barrier(0);

  f32x4 acc[8][NSUB] = {};
  bf16x8 bfr[NSUB][2], bnx[2][2];

#pragma unroll
  for (int n = 0; n < 2; n++) {
    const int r = wc * (16*NSUB) + n * 16 + l16;
#pragma unroll
    for (int ks = 0; ks < 2; ks++) {
      const int cb = ks * 64 + lhi * 16;
      bnx[n][ks] = *(const bf16x8*)(smem + 65536u + r * 128 + (cb ^ ((r & 7) << 4)));
    }
  }

  for (int kt = 0; kt < NKT; kt++) {
    const int cur = kt & 1;
    const uint32_t aB = cur * 32768u;
    const uint32_t bB = 65536u + cur * (8192u*NSUB);
#pragma unroll
    for (int p = 0; p < 4; p++) {
      if (p == 0) {
#pragma unroll
        for (int n = 0; n < 2; n++)
#pragma unroll
          for (int ks = 0; ks < 2; ks++) bfr[n][ks] = bnx[n][ks];
        if constexpr (NSUB == 4) {
#pragma unroll
          for (int n = 2; n < 4; n++) {
            const int r = wc * (16*NSUB) + n * 16 + l16;
#pragma unroll
            for (int ks = 0; ks < 2; ks++) {
              const int cb = ks * 64 + lhi * 16;
              bfr[n][ks] = *(const bf16x8*)(smem + bB + r * 128 + (cb ^ ((r & 7) << 4)));
            }
          }
        }
      }
      bf16x8 afr[2][2];
#pragma unroll
      for (int mm = 0; mm < 2; mm++) {
        const int r = wr * 128 + p * 32 + mm * 16 + l16;
#pragma unroll
        for (int ks = 0; ks < 2; ks++) {
          const int cb = ks * 64 + lhi * 16;
          afr[mm][ks] = *(const bf16x8*)(smem + aB + r * 128 + (cb ^ ((r & 7) << 4)));
        }
      }
      const int h = 4 * kt + p + 6;
      if (h < 4 * NKT) stage(h);
      __builtin_amdgcn_sched_barrier(0);       // loads+stage issued before MFMA
      __builtin_amdgcn_s_setprio(1);
#pragma unroll
      for (int mm = 0; mm < 2; mm++)
#pragma unroll
        for (int n = 0; n < NSUB; n++)
#pragma unroll
          for (int ks = 0; ks < 2; ks++)
            acc[2 * p + mm][n] = __builtin_amdgcn_mfma_f32_16x16x32_bf16(
                afr[mm][ks], bfr[n][ks], acc[2 * p + mm][n], 0, 0, 0);
      __builtin_amdgcn_s_setprio(0);
      if (p == 2) {
        if constexpr (NSUB == 4) asm volatile("s_waitcnt vmcnt(6)" ::: "memory");
        else                     asm volatile("s_waitcnt vmcnt(5)" ::: "memory");
      }
      if (p == 3) {
        if (kt < NKT - 2) {
          if constexpr (NSUB == 4) asm volatile("s_waitcnt vmcnt(4)" ::: "memory");
          else                     asm volatile("s_waitcnt vmcnt(2)" ::: "memory");
        } else if (kt == NKT - 2) {
          asm volatile("s_waitcnt vmcnt(0)" ::: "memory");
        }
        if (kt + 1 < NKT) {
          const uint32_t bN = 65536u + ((kt + 1) & 1) * (8192u*NSUB);
#pragma unroll
          for (int n = 0; n < 2; n++) {
            const int r = wc * (16*NSUB) + n * 16 + l16;
#pragma unroll
            for (int ks = 0; ks < 2; ks++) {
              const int cb = ks * 64 + lhi * 16;
              bnx[n][ks] = *(const bf16x8*)(smem + bN + r * 128 + (cb ^ ((r & 7) << 4)));
            }
          }
        }
      }
      __builtin_amdgcn_s_barrier();            // single per-phase rendezvous
      asm volatile("" ::: "memory");
      __builtin_amdgcn_sched_barrier(0);
    }
  }

#pragma unroll
  for (int m = 0; m < 8; m++) {
    const int rbase = rowT0 + wr * 128 + m * 16 + lhi * 4;
#pragma unroll
    for (int n = 0; n < NSUB; n++) {
      const int col = colT0 + wc * (16*NSUB) + n * 16 + l16;
      const float bv = bias[col];
#pragma unroll
      for (int j = 0; j < 4; j++) {
        float v = acc[m][n][j] + bv;
        if (OUT_BF16) ((bf16_t*)Cout)[(size_t)(rbase + j) * ldc + col] = __float2bfloat16(v);
        else          ((float*)Cout)[(size_t)(rbase + j) * ldc + col] = v;
      }
    }
  }
}

// ------- per-chunk KV^T = V^T . K'  (rotary-on-k via trig table) ------------
__global__ __launch_bounds__(256)
void chunk_kvt_kernel(const bf16_t* __restrict__ kb, const bf16_t* __restrict__ vb,
                      const float2* __restrict__ trig, bf16_t* __restrict__ kvt) {
  __shared__ alignas(16) char lds[32768];
  char* vts = lds;
  char* kts = lds + 16384;

  const int tid = threadIdx.x, wave = tid >> 6, lane = tid & 63;
  const int l16 = lane & 15, lhi = lane >> 4;
  const int blk = blockIdx.x;              // bh*NC + ch
  const int bh = blk >> 5, ch = blk & 31;
  const int h = bh & (H_ - 1);
  const float log2g = head_log2g(h);
  const int n0 = ch * 64;

  const size_t bhbase = (size_t)(bh >> 4) * N_ * QKVG_LD + (size_t)h * 128;

#pragma unroll
  for (int it = 0; it < 4; it++) {
    int j = it*16 + (tid >> 4);
    int e0 = (tid & 15) * 8;
    bf16x8 vv = *(const bf16x8*)(vb + bhbase + (size_t)(n0 + j)*QKVG_LD + e0);
    bf16x8 kk = *(const bf16x8*)(kb + bhbase + (size_t)(n0 + j)*QKVG_LD + e0);
    const float2* tr = trig + (size_t)(n0 + j)*64 + (tid & 15)*4;
    float kvd = exp2f((float)(63 - j) * log2g) * KS_;
    float kr[8];
#pragma unroll
    for (int p = 0; p < 4; p++) {
      float2 cs = tr[p];
      float a = (float)kk[2*p], b2 = (float)kk[2*p+1];
      kr[2*p]   = (a*cs.x - b2*cs.y);
      kr[2*p+1] = (b2*cs.x + a*cs.y);
    }
#pragma unroll
    for (int m = 0; m < 8; m++) {
      int e = e0 + m;
      *(__bf16*)(vts + e*128 + ((j*2) ^ ((e&7)<<4))) = vv[m];
      *(__bf16*)(kts + e*128 + ((j*2) ^ ((e&7)<<4))) = (__bf16)(kr[m] * kvd);
    }
  }
  __syncthreads();

  f32x4 acc[2][8] = {};
#pragma unroll
  for (int kk2 = 0; kk2 < 2; kk2++) {
#pragma unroll
    for (int et = 0; et < 2; et++) {
      int e = (2*wave + et)*16 + l16;
      bf16x8 vf = *(const bf16x8*)(vts + e*128 + (((kk2*32 + lhi*8)*2) ^ ((e&7)<<4)));
#pragma unroll
      for (int dt = 0; dt < 8; dt++) {
        int d = dt*16 + l16;
        bf16x8 kf = *(const bf16x8*)(kts + d*128 + (((kk2*32 + lhi*8)*2) ^ ((d&7)<<4)));
        acc[et][dt] = __builtin_amdgcn_mfma_f32_16x16x32_bf16(vf, kf, acc[et][dt], 0, 0, 0);
      }
    }
  }

  const size_t obase = (size_t)blk * 16384;
#pragma unroll
  for (int et = 0; et < 2; et++)
#pragma unroll
    for (int dt = 0; dt < 8; dt++)
#pragma unroll
      for (int j = 0; j < 4; j++) {
        int e = (2*wave + et)*16 + lhi*4 + j;
        int d = dt*16 + l16;
        kvt[obase + e*128 + d] = __float2bfloat16(acc[et][dt][j]);
      }
}

// ---------------- state scan over chunks (2 elems/thread) ------------------
__global__ __launch_bounds__(256)
void state_scan_kernel(const bf16_t* __restrict__ kvt, const float* __restrict__ prev,
                       bf16_t* __restrict__ sbft, float* __restrict__ out_state) {
  int t = blockIdx.x * 256 + threadIdx.x;     // over B*H*8192
  int bh = t >> 13;
  int ed = (t & 8191) * 2;
  int e = ed >> 7, d = ed & 127;              // d even, d+1 same e
  int h = bh & (H_ - 1);
  const float cdecay = exp2f(64.0f * head_log2g(h));

  float S0 = prev[(size_t)bh*16384 + (size_t)d*128 + e];
  float S1 = prev[(size_t)bh*16384 + (size_t)(d+1)*128 + e];
  size_t boff = ((size_t)bh * (NC_*16384) + ed) >> 1;     // uint index
  const unsigned int* kv2 = (const unsigned int*)kvt;
  unsigned int* sb2 = (unsigned int*)sbft;
  for (int ch = 0; ch < NC_; ch++) {
    sb2[boff] = (unsigned int)f2bfu(S0) | ((unsigned int)f2bfu(S1) << 16);
    unsigned int kv = kv2[boff];
    S0 = S0 * cdecay + bfu2f((unsigned short)(kv & 0xffff));
    S1 = S1 * cdecay + bfu2f((unsigned short)(kv >> 16));
    boff += 8192;
  }
  out_state[(size_t)bh*16384 + (size_t)d*128 + e]     = S0;
  out_state[(size_t)bh*16384 + (size_t)(d+1)*128 + e] = S1;
}

// --- per-chunk output + fused GroupNorm*SiLU(gate), rotary via trig table ---
// r10: GroupNorm done fully in-register. Row i = wave*16+lhi*4+j lives in one
// 16-lane l16 group (8 et x 16 l16 = 128 cols) -> width-16 shfl_xor reduce,
// no o_lds round-trip, no extra barriers.
__global__ __launch_bounds__(256)
void chunk_out_kernel(const bf16_t* __restrict__ qb, const bf16_t* __restrict__ kb,
                      const bf16_t* __restrict__ vb, const bf16_t* __restrict__ gb,
                      const bf16_t* __restrict__ sbft, const float2* __restrict__ trig,
                      bf16_t* __restrict__ gated) {
  __shared__ alignas(16) char lds[24576];
  char* vts = lds;                 // V^T 16KB
  char* ats = lds + 16384;         // att 8KB

  const int tid = threadIdx.x, wave = tid >> 6, lane = tid & 63;
  const int l16 = lane & 15, lhi = lane >> 4;
  const int blk = blockIdx.x;              // bh*NC + ch
  const int bh = blk >> 5, ch = blk & 31;
  const int h = bh & (H_ - 1);
  const int b = bh >> 4;
  const float log2g = head_log2g(h);
  const int n0 = ch * 64;

  const size_t bhbase = (size_t)b * N_ * QKVG_LD + (size_t)h * 128;
  const bf16_t* Srow = sbft + (size_t)blk * 16384;   // [e][d]

#pragma unroll
  for (int it = 0; it < 4; it++) {
    int j = it*16 + (tid >> 4);
    int e0 = (tid & 15) * 8;
    bf16x8 vv = *(const bf16x8*)(vb + bhbase + (size_t)(n0 + j)*QKVG_LD + e0);
#pragma unroll
    for (int m = 0; m < 8; m++) {
      int e = e0 + m;
      *(__bf16*)(vts + e*128 + ((j*2) ^ ((e&7)<<4))) = vv[m];
    }
  }

  // q fragments with rotary (row = n0 + wave*16 + l16)
  const float2* trq = trig + (size_t)(n0 + wave*16 + l16)*64;
  bf16x8 qf[4];
#pragma unroll
  for (int dk = 0; dk < 4; dk++) {
    bf16x8 qv = *(const bf16x8*)(qb + bhbase + (size_t)(n0 + wave*16 + l16)*QKVG_LD + dk*32 + lhi*8);
#pragma unroll
    for (int p = 0; p < 4; p++) {
      float2 cs = trq[dk*16 + lhi*4 + p];
      float a = (float)qv[2*p], b2 = (float)qv[2*p+1];
      qf[dk][2*p]   = (__bf16)(a*cs.x - b2*cs.y);
      qf[dk][2*p+1] = (__bf16)(b2*cs.x + a*cs.y);
    }
  }

  // att = (q k^T) * Dmat, rotary+KS on k fragments
  f32x4 aacc[4] = {};
#pragma unroll
  for (int jt = 0; jt < 4; jt++) {
    const float2* trk = trig + (size_t)(n0 + jt*16 + l16)*64;
#pragma unroll
    for (int dk = 0; dk < 4; dk++) {
      bf16x8 kv = *(const bf16x8*)(kb + bhbase + (size_t)(n0 + jt*16 + l16)*QKVG_LD + dk*32 + lhi*8);
      bf16x8 kf;
#pragma unroll
      for (int p = 0; p < 4; p++) {
        float2 cs = trk[dk*16 + lhi*4 + p];
        float a = (float)kv[2*p], b2 = (float)kv[2*p+1];
        kf[2*p]   = (__bf16)((a*cs.x - b2*cs.y) * KS_);
        kf[2*p+1] = (__bf16)((b2*cs.x + a*cs.y) * KS_);
      }
      aacc[jt] = __builtin_amdgcn_mfma_f32_16x16x32_bf16(qf[dk], kf, aacc[jt], 0, 0, 0);
    }
  }
#pragma unroll
  for (int jt = 0; jt < 4; jt++)
#pragma unroll
    for (int j = 0; j < 4; j++) {
      int i = wave*16 + lhi*4 + j;
      int jc = jt*16 + l16;
      aacc[jt][j] *= (i >= jc) ? exp2f((float)(i - jc) * log2g) : 0.0f;
    }

#pragma unroll
  for (int jt = 0; jt < 4; jt++)
#pragma unroll
    for (int j = 0; j < 4; j++) {
      int i = wave*16 + lhi*4 + j;
      int jc = jt*16 + l16;
      *(__bf16*)(ats + i*128 + ((jc*2) ^ ((i&7)<<4))) = (__bf16)aacc[jt][j];
    }
  __syncthreads();

  f32x4 oacc[8] = {};
#pragma unroll
  for (int et = 0; et < 8; et++) {
#pragma unroll
    for (int dk = 0; dk < 4; dk++) {
      int e = et*16 + l16;
      bf16x8 sf = *(const bf16x8*)(Srow + e*128 + dk*32 + lhi*8);
      oacc[et] = __builtin_amdgcn_mfma_f32_16x16x32_bf16(qf[dk], sf, oacc[et], 0, 0, 0);
    }
  }
#pragma unroll
  for (int j = 0; j < 4; j++) {
    int i = wave*16 + lhi*4 + j;
    float f = exp2f((float)(i + 1) * log2g);
#pragma unroll
    for (int et = 0; et < 8; et++) oacc[et][j] *= f;
  }

#pragma unroll
  for (int kk2 = 0; kk2 < 2; kk2++) {
    int i = wave*16 + l16;
    bf16x8 af = *(const bf16x8*)(ats + i*128 + (((kk2*32 + lhi*8)*2) ^ ((i&7)<<4)));
#pragma unroll
    for (int et = 0; et < 8; et++) {
      int e = et*16 + l16;
      bf16x8 vf = *(const bf16x8*)(vts + e*128 + (((kk2*32 + lhi*8)*2) ^ ((e&7)<<4)));
      oacc[et] = __builtin_amdgcn_mfma_f32_16x16x32_bf16(af, vf, oacc[et], 0, 0, 0);
    }
  }

  // ---- in-register GroupNorm + SiLU gate (width-16 reduce per row) ----
#pragma unroll
  for (int j = 0; j < 4; j++) {
    float s = 0.0f, ss = 0.0f;
#pragma unroll
    for (int et = 0; et < 8; et++) {
      float v = oacc[et][j];
      s += v; ss += v * v;
    }
#pragma unroll
    for (int off = 1; off < 16; off <<= 1) {
      s  += __shfl_xor(s, off);
      ss += __shfl_xor(ss, off);
    }
    float mu  = s * (1.0f/128.0f);
    float inv = rsqrtf(ss * (1.0f/128.0f) - mu*mu + 1e-6f);
    const int i = wave*16 + lhi*4 + j;
    const size_t grow = (size_t)b * N_ + (n0 + i);
#pragma unroll
    for (int et = 0; et < 8; et++) {
      const int col = et*16 + l16;
      float g0 = bfu2f(*(const unsigned short*)(gb + grow*QKVG_LD + h*128 + col));
      float r0 = (oacc[et][j] - mu) * inv * (g0 / (1.0f + expf(-g0)));
      *(unsigned short*)(gated + grow*2048 + h*128 + col) = f2bfu(r0);
    }
  }
}

// ---------------- launch ----------------
extern "C" void kernel_launch(void* const* d_in, const int* in_sizes, int n_in,
                              void* d_out, int out_size, void* d_ws, size_t ws_size,
                              hipStream_t stream) {
  const float* x    = (const float*)d_in[0];
  const float* prev = (const float*)d_in[1];
  const float* Wq = (const float*)d_in[2];  const float* bq = (const float*)d_in[3];
  const float* Wk = (const float*)d_in[4];  const float* bk = (const float*)d_in[5];
  const float* Wv = (const float*)d_in[6];  const float* bv = (const float*)d_in[7];
  const float* Wg = (const float*)d_in[8];  const float* bg = (const float*)d_in[9];
  const float* Wo = (const float*)d_in[10]; const float* bo = (const float*)d_in[11];
  const int* startp = (const int*)d_in[12];

  float* out = (float*)d_out;                               // B*N*E
  float* out_state = out + (size_t)B_*N_*E_;                // B*H*DQK*DV
  float2* trig = (float2*)out;   // 1MB at d_out head; dead until final GEMM

  char* w = (char*)d_ws;
  const size_t XN = (size_t)B_*N_*E_;       // 8388608
  const size_t WN = (size_t)E_*E_;          // 4194304
  bf16_t* xb   = (bf16_t*)w;             w += XN*2;                  // 16MB (reused as gated)
  bf16_t* qkvg = (bf16_t*)w;             w += (size_t)M_*QKVG_LD*2;  // 64MB
  bf16_t* wob  = (bf16_t*)w;             w += WN*2;                  // 8MB
  char*   wcat_region = w;               w += 4*WN*2;                // 32MB
  bf16_t* wcat = (bf16_t*)wcat_region;
  bf16_t* sbft = (bf16_t*)w;             w += (size_t)B_*H_*NC_*16384*2; // 32MB
  bf16_t* kvt   = (bf16_t*)wcat_region;  // alias (wcat dead after QKVG GEMM)
  float*  bcat  = (float*)sbft;   // 32KB at sbft head; consumed before state_scan

  hipFuncSetAttribute(reinterpret_cast<const void*>(gemm8_kernel<true,4>),
                      hipFuncAttributeMaxDynamicSharedMemorySize, 131072);
  hipFuncSetAttribute(reinterpret_cast<const void*>(gemm8_kernel<false,2>),
                      hipFuncAttributeMaxDynamicSharedMemorySize, 98304);

  cvt_all_kernel<<<29192, 256, 0, stream>>>(x, Wq, Wk, Wv, Wg, Wo, bq, bk, bv, bg,
                                            startp, xb, wcat, wob, bcat, trig);

  // fused QKVG projection: [4096,2048] @ [8192,2048]^T -> [4096,8192]
  gemm8_kernel<true,4><<<512, 512, 131072, stream>>>(xb, wcat, bcat, (void*)qkvg,
                                                     E_, QKVG_LD, 16 /*tilesM*/);

  chunk_kvt_kernel<<<B_*H_*NC_, 256, 0, stream>>>(qkvg + 2048, qkvg + 4096,
                                                  trig, kvt);
  state_scan_kernel<<<1024, 256, 0, stream>>>(kvt, prev, sbft, out_state);
  chunk_out_kernel<<<B_*H_*NC_, 256, 0, stream>>>(qkvg, qkvg + 2048, qkvg + 4096,
                                                  qkvg + 6144, sbft, trig,
                                                  xb /*gated*/);

  // output projection: [4096,2048] @ [2048,2048]^T -> [4096,2048] f32
  gemm8_kernel<false,2><<<256, 512, 98304, stream>>>(xb, wob, bo, (void*)out,
                                                     E_, E_, 16 /*tilesM*/);
}